// Round 12
// baseline (78.455 us; speedup 1.0000x reference)
//
#include <hip/hip_runtime.h>
#include <stdint.h>

typedef unsigned long long u64;
typedef __attribute__((ext_vector_type(8))) short short8;   // 8 x bf16 (4 VGPR)
typedef __attribute__((ext_vector_type(4))) float f32x4;    // MFMA C/D frag

#define B_ 32
#define N_ 512
#define FIN_ 80
#define FH_ 50
#define FO_ 80
#define CAT_ 150
#define KP_ 160   // padded K for layer-2 (150 + 9 dontcare + 1 ones@159)
#define NP_ 96    // WoutT leading dim

__device__ inline unsigned short f2bf(float f) {  // RNE float -> bf16 bits
  unsigned u = __float_as_uint(f);
  u += 0x7fffu + ((u >> 16) & 1u);
  return (unsigned short)(u >> 16);
}

__device__ inline unsigned nib4(int4 v) {
  return (v.x != 0 ? 1u : 0u) | (v.y != 0 ? 2u : 0u) |
         (v.z != 0 ? 4u : 0u) | (v.w != 0 ? 8u : 0u);
}

// A-fragment builder: p = exp(min(lrelu(e1+e2),60)) masked, bf16
__device__ inline short8 build_af(const float* e2s, float e1r, u64 word,
                                  int jb, int shift) {
  short8 af;
  unsigned b0 = (unsigned)(word >> shift) & 0xffu;
  float4 va = *(const float4*)&e2s[jb];
  float4 vb = *(const float4*)&e2s[jb + 4];
  float ev[8] = {va.x, va.y, va.z, va.w, vb.x, vb.y, vb.z, vb.w};
  #pragma unroll
  for (int e = 0; e < 8; ++e) {
    float sv = e1r + ev[e];
    sv = fmaxf(sv, 0.2f * sv);
    sv = fminf(sv, 60.f);
    float arg = ((b0 >> e) & 1u) ? sv : -1e30f;
    af[e] = (short)f2bf(__expf(arg));
  }
  return af;
}

// ---------- k0: 0..2047 mask (tiny LDS, full occupancy) | 2048..2062 WoutT | 2063 wv
__global__ __launch_bounds__(256) void k0_maskprep(const int* __restrict__ adj,
                                                   const float* __restrict__ Wout,
                                                   const float* __restrict__ a_out,
                                                   u64* __restrict__ maskw,
                                                   unsigned short* __restrict__ WoutT,
                                                   float* __restrict__ wv1,
                                                   float* __restrict__ wv2) {
  __shared__ unsigned short sm[256];
  const int t = threadIdx.x;
  const int bid = blockIdx.x;

  if (bid < 2048) {  // ---- mask: 8 rows/block ----
    const int r = t >> 5, s = t & 31;
    const int row = bid * 8 + r;
    const int4* src = (const int4*)(adj + (size_t)row * N_ + s * 16);
    int4 v0 = src[0], v1 = src[1], v2 = src[2], v3 = src[3];  // 4 indep 16B loads
    unsigned m = nib4(v0) | (nib4(v1) << 4) | (nib4(v2) << 8) | (nib4(v3) << 12);
    sm[t] = (unsigned short)m;
    __syncthreads();
    if (t < 64) {
      const int rr = t >> 3, w = t & 7;
      const unsigned short* p = &sm[rr * 32 + w * 4];
      u64 mm = (u64)p[0] | ((u64)p[1] << 16) | ((u64)p[2] << 32) | ((u64)p[3] << 48);
      maskw[(size_t)(bid * 8 + rr) * 8 + w] = mm;
    }
    return;
  }
  if (bid < 2063) {  // ---- WoutT[col 96][k 160] bf16: 1 uint2/thread ----
    const int i = (bid - 2048) * 256 + t;
    const int base = i * 4;
    const int col = base / KP_, k0 = base % KP_;
    unsigned short pk[4];
    #pragma unroll
    for (int e = 0; e < 4; ++e) {
      const int k = k0 + e;
      pk[e] = (col < FO_ && k < CAT_) ? f2bf(Wout[(size_t)k * FO_ + col]) : 0;
    }
    uint2 o;
    o.x = (unsigned)pk[0] | ((unsigned)pk[1] << 16);
    o.y = (unsigned)pk[2] | ((unsigned)pk[3] << 16);
    ((uint2*)WoutT)[i] = o;
    return;
  }
  // ---- wv1/wv2[k] = Wout[k][:] . a_out halves ----
  if (t < CAT_) {
    const float4* wr = (const float4*)(Wout + (size_t)t * FO_);
    const float4* a1 = (const float4*)a_out;
    const float4* a2 = (const float4*)(a_out + FO_);
    float p1 = 0.f, p2 = 0.f;
    #pragma unroll
    for (int i = 0; i < 20; ++i) {
      float4 v = wr[i], x1 = a1[i], x2 = a2[i];
      p1 += v.x * x1.x + v.y * x1.y + v.z * x1.z + v.w * x1.w;
      p2 += v.x * x2.x + v.y * x2.y + v.z * x2.z + v.w * x2.w;
    }
    wv1[t] = p1; wv2[t] = p2;
  }
}

// ---------- k1: Wh via MFMA; e1h/e2h from MFMA accs; whT bf16 [col64][j512] -------
__global__ __launch_bounds__(256) void k1_mfma(const float* __restrict__ h,
                                               const float* __restrict__ Ws,
                                               const float* __restrict__ attn_a,
                                               unsigned short* __restrict__ whT,
                                               float* __restrict__ e1h,
                                               float* __restrict__ e2h) {
  __shared__ __align__(16) unsigned short un[64 * 104];    // h bf16; reused as tbT[64][72]
  __shared__ __align__(16) unsigned short bstage[12 * 512]; // Ws B-frags
  const int t = threadIdx.x;
  int x = blockIdx.x;
  const int rt = x & 7; x >>= 3;
  const int bb = x & 31; x >>= 5;
  const int hh = x;
  const int n0 = rt * 64;
  const float* hblk = h + ((size_t)bb * N_ + n0) * FIN_;
  const float* wsrc = Ws + (size_t)hh * FIN_ * FH_;

  for (int idx = t; idx < 64 * 13; idx += 256) {  // h tile bf16 [64][104]
    const int row = idx / 13, k0 = (idx - row * 13) * 8;
    short8 v8;
    if (k0 < FIN_) {
      float4 a = *(const float4*)(hblk + row * FIN_ + k0);
      float4 b = *(const float4*)(hblk + row * FIN_ + k0 + 4);
      v8[0] = (short)f2bf(a.x); v8[1] = (short)f2bf(a.y);
      v8[2] = (short)f2bf(a.z); v8[3] = (short)f2bf(a.w);
      v8[4] = (short)f2bf(b.x); v8[5] = (short)f2bf(b.y);
      v8[6] = (short)f2bf(b.z); v8[7] = (short)f2bf(b.w);
    } else {
      #pragma unroll
      for (int e = 0; e < 8; ++e) v8[e] = 0;
    }
    *(short8*)&un[row * 104 + k0] = v8;
  }
  for (int idx = t; idx < 768; idx += 256) {  // B-frags from Ws (L2-cached)
    const int f = idx >> 6, lf = idx & 63;
    const int ks = f >> 2, nt = f & 3;
    const int kb = ks * 32 + (lf >> 4) * 8, n = nt * 16 + (lf & 15);
    short8 v8;
    #pragma unroll
    for (int e = 0; e < 8; ++e) {
      const int k = kb + e;
      v8[e] = (k < FIN_ && n < FH_) ? (short)f2bf(wsrc[k * FH_ + n]) : (short)0;
    }
    *(short8*)&bstage[idx * 8] = v8;
  }
  __syncthreads();

  const int l = t & 63, wv = t >> 6, q = l >> 4, rl = l & 15;
  f32x4 acc[4];
  {
    short8 af[3];
    #pragma unroll
    for (int ks = 0; ks < 3; ++ks)
      af[ks] = *(const short8*)&un[(wv * 16 + rl) * 104 + ks * 32 + q * 8];
    #pragma unroll
    for (int nt = 0; nt < 4; ++nt) acc[nt] = (f32x4){0.f, 0.f, 0.f, 0.f};
    #pragma unroll
    for (int ks = 0; ks < 3; ++ks)
      #pragma unroll
      for (int nt = 0; nt < 4; ++nt)
        acc[nt] = __builtin_amdgcn_mfma_f32_16x16x32_bf16(
            af[ks], *(const short8*)&bstage[((ks * 4 + nt) * 64 + l) * 8], acc[nt], 0, 0, 0);
  }
  {  // e1/e2 from f32 accumulators: e[j] = sum_col Wh[j][col]*a[col]
    float a1v[4], a2v[4];
    #pragma unroll
    for (int c = 0; c < 4; ++c) {
      const int col = c * 16 + rl;
      a1v[c] = (col < FH_) ? attn_a[hh * 2 * FH_ + col] : 0.f;
      a2v[c] = (col < FH_) ? attn_a[hh * 2 * FH_ + FH_ + col] : 0.f;
    }
    #pragma unroll
    for (int r = 0; r < 4; ++r) {
      float p1 = acc[0][r] * a1v[0] + acc[1][r] * a1v[1] +
                 acc[2][r] * a1v[2] + acc[3][r] * a1v[3];
      float p2 = acc[0][r] * a2v[0] + acc[1][r] * a2v[1] +
                 acc[2][r] * a2v[2] + acc[3][r] * a2v[3];
      p1 += __shfl_xor(p1, 1); p1 += __shfl_xor(p1, 2);
      p1 += __shfl_xor(p1, 4); p1 += __shfl_xor(p1, 8);
      p2 += __shfl_xor(p2, 1); p2 += __shfl_xor(p2, 2);
      p2 += __shfl_xor(p2, 4); p2 += __shfl_xor(p2, 8);
      if (rl == 0) {
        size_t o = ((size_t)hh * B_ + bb) * N_ + n0 + wv * 16 + q * 4 + r;
        e1h[o] = p1; e2h[o] = p2;
      }
    }
  }
  __syncthreads();   // un reads done -> reuse as tbT
  unsigned short* tbT = un;  // [col][j], stride 72
  #pragma unroll
  for (int nt = 0; nt < 4; ++nt)
    #pragma unroll
    for (int r2 = 0; r2 < 4; ++r2)
      tbT[(nt * 16 + rl) * 72 + wv * 16 + q * 4 + r2] = f2bf(acc[nt][r2]);
  __syncthreads();
  {  // emit whT[col][j] coalesced; col 63 = ones (layer-1 denominator)
    const int col = t & 63, half = t >> 6;
    uint4 o0 = *(const uint4*)&tbT[col * 72 + half * 16];
    uint4 o1 = *(const uint4*)&tbT[col * 72 + half * 16 + 8];
    if (col == 63) {
      o0.x = o0.y = o0.z = o0.w = 0x3f803f80u;
      o1 = o0;
    }
    unsigned short* dst = whT + (((size_t)hh * B_ + bb) * 64 + col) * 512 + n0 + half * 16;
    *(uint4*)dst = o0;
    *(uint4*)(dst + 8) = o1;
  }
}

// ---------- k3s: layer-1 attention, 64 rows/block (wave-owned 16-row groups) ------
__global__ __launch_bounds__(256) void k3s(const unsigned short* __restrict__ whT,
                                           const float* __restrict__ e1,
                                           const float* __restrict__ e2,
                                           const u64* __restrict__ maskw,
                                           const float* __restrict__ wv1,
                                           const float* __restrict__ wv2,
                                           unsigned short* __restrict__ catT,
                                           float* __restrict__ e1p,
                                           float* __restrict__ e2p) {
  __shared__ __align__(16) float e2s[N_];
  int x = (int)((blockIdx.x & 7) * 96 + (blockIdx.x >> 3));  // bijective (768 = 8*96)
  const int rt = x & 7; x >>= 3;
  const int bb = x & 31; x >>= 5;
  const int hh = x;
  const int n0 = rt * 64;
  const int t = threadIdx.x;
  const int l = t & 63, wid = t >> 6;
  const int q = l >> 4, rl = l & 15;

  const float* e2pp = e2 + ((size_t)hh * B_ + bb) * N_;
  for (int i = t; i < N_ / 4; i += 256) ((float4*)e2s)[i] = ((const float4*)e2pp)[i];
  __syncthreads();

  const int row = n0 + wid * 16 + rl;     // each wave owns 16 rows, all j
  const float e1r = e1[((size_t)hh * B_ + bb) * N_ + row];
  const u64* mr = maskw + ((size_t)bb * N_ + row) * 8;

  f32x4 acc[4];
  #pragma unroll
  for (int c = 0; c < 4; ++c) acc[c] = (f32x4){0.f, 0.f, 0.f, 0.f};
  const unsigned short* wb = whT + ((size_t)hh * B_ + bb) * 64 * 512;

  for (int tt = 0; tt < 8; ++tt) {
    short8 bf[4][2];
    #pragma unroll
    for (int c = 0; c < 4; ++c) {
      const unsigned short* bp = wb + (size_t)(c * 16 + rl) * 512 + tt * 64 + q * 8;
      bf[c][0] = *(const short8*)bp;
      bf[c][1] = *(const short8*)(bp + 32);
    }
    u64 word = mr[tt];
    short8 af0 = build_af(e2s, e1r, word, tt * 64 + q * 8, q * 8);
    short8 af1 = build_af(e2s, e1r, word, tt * 64 + 32 + q * 8, 32 + q * 8);
    #pragma unroll
    for (int c = 0; c < 4; ++c) {
      acc[c] = __builtin_amdgcn_mfma_f32_16x16x32_bf16(af0, bf[c][0], acc[c], 0, 0, 0);
      acc[c] = __builtin_amdgcn_mfma_f32_16x16x32_bf16(af1, bf[c][1], acc[c], 0, 0, 0);
    }
  }

  // epilogue: fully wave-parallel (no cross-wave reduce)
  float w1c[4], w2c[4];
  #pragma unroll
  for (int c = 0; c < 4; ++c) {
    const int col = c * 16 + rl;
    w1c[c] = (col < FH_) ? wv1[hh * FH_ + col] : 0.f;
    w2c[c] = (col < FH_) ? wv2[hh * FH_ + col] : 0.f;
  }
  #pragma unroll
  for (int r = 0; r < 4; ++r) {
    float srow = __shfl(acc[3][r], (q << 4) | 15);  // col 63 = denom (ones col)
    float invr = srow > 0.f ? 1.f / srow : 0.f;
    const int jrow = n0 + wid * 16 + q * 4 + r;
    const size_t grow = (size_t)bb * N_ + jrow;
    float p1 = 0.f, p2 = 0.f;
    #pragma unroll
    for (int c = 0; c < 4; ++c) {
      const int col = c * 16 + rl;
      if (col < FH_) {
        float v = acc[c][r] * invr;
        v = v > 0.f ? v : __expf(v) - 1.f;  // ELU
        catT[((size_t)bb * KP_ + hh * FH_ + col) * 512 + jrow] = f2bf(v);
        p1 += v * w1c[c];
        p2 += v * w2c[c];
      }
    }
    p1 += __shfl_xor(p1, 1); p1 += __shfl_xor(p1, 2);
    p1 += __shfl_xor(p1, 4); p1 += __shfl_xor(p1, 8);
    p2 += __shfl_xor(p2, 1); p2 += __shfl_xor(p2, 2);
    p2 += __shfl_xor(p2, 4); p2 += __shfl_xor(p2, 8);
    if (rl == 0) {
      e1p[(size_t)hh * (B_ * N_) + grow] = p1;
      e2p[(size_t)hh * (B_ * N_) + grow] = p2;
    }
  }
  // ones column only (kcol 159 = denominator); kcols 150..158 hit zero WoutT rows
  if (hh == 2 && t < 64)
    catT[((size_t)bb * KP_ + (KP_ - 1)) * 512 + n0 + t] = (unsigned short)0x3f80;
}

// ---------- kC: out = (P . catT) @ Wout / denom  (k4+k5 fused) --------------------
__global__ __launch_bounds__(256) void kC(const unsigned short* __restrict__ catT,
                                          const unsigned short* __restrict__ WoutT,
                                          const float* __restrict__ e1p,
                                          const float* __restrict__ e2p,
                                          const u64* __restrict__ maskw,
                                          float* __restrict__ out) {
  __shared__ __align__(16) float e2s[N_];
  __shared__ __align__(16) float red[3][64][41];
  __shared__ __align__(16) unsigned short pA[16 * 168];
  __shared__ float denomLDS[16];
  int x = (int)((blockIdx.x & 7) * 128 + (blockIdx.x >> 3));
  const int rg = x & 31;
  const int bb = x >> 5;
  const int n0 = rg * 16;
  const int t = threadIdx.x;
  const int l = t & 63, wid = t >> 6;
  const int q = l >> 4, rl = l & 15;

  for (int i = t; i < N_ / 4; i += 256) {
    float4 v0 = ((const float4*)(e2p))[(size_t)bb * 128 + i];
    float4 v1 = ((const float4*)(e2p + B_ * N_))[(size_t)bb * 128 + i];
    float4 v2 = ((const float4*)(e2p + 2 * B_ * N_))[(size_t)bb * 128 + i];
    float4 s;
    s.x = v0.x + v1.x + v2.x; s.y = v0.y + v1.y + v2.y;
    s.z = v0.z + v1.z + v2.z; s.w = v0.w + v1.w + v2.w;
    ((float4*)e2s)[i] = s;
  }
  __syncthreads();

  const int row = n0 + rl;
  const size_t gr = (size_t)bb * N_ + row;
  const float e1r = e1p[gr] + e1p[B_ * N_ + gr] + e1p[2 * B_ * N_ + gr];
  const u64* mr = maskw + gr * 8;

  f32x4 acc[10];
  #pragma unroll
  for (int c = 0; c < 10; ++c) acc[c] = (f32x4){0.f, 0.f, 0.f, 0.f};
  const unsigned short* cb = catT + (size_t)bb * KP_ * 512;

  #pragma unroll
  for (int tts = 0; tts < 2; ++tts) {
    const int tt = wid * 2 + tts;
    u64 word = mr[tt];
    short8 af0 = build_af(e2s, e1r, word, tt * 64 + q * 8, q * 8);
    short8 af1 = build_af(e2s, e1r, word, tt * 64 + 32 + q * 8, 32 + q * 8);
    #pragma unroll
    for (int c = 0; c < 10; ++c) {
      const unsigned short* bp = cb + (size_t)(c * 16 + rl) * 512 + tt * 64 + q * 8;
      short8 b0 = *(const short8*)bp;
      short8 b1 = *(const short8*)(bp + 32);
      acc[c] = __builtin_amdgcn_mfma_f32_16x16x32_bf16(af0, b0, acc[c], 0, 0, 0);
      acc[c] = __builtin_amdgcn_mfma_f32_16x16x32_bf16(af1, b1, acc[c], 0, 0, 0);
    }
  }

  if (wid > 0) {
    #pragma unroll
    for (int c = 0; c < 10; ++c)
      #pragma unroll
      for (int r = 0; r < 4; ++r) red[wid - 1][l][c * 4 + r] = acc[c][r];
  }
  __syncthreads();

  if (wid == 0) {
    #pragma unroll
    for (int c = 0; c < 10; ++c)
      #pragma unroll
      for (int r = 0; r < 4; ++r) {
        const int idx = c * 4 + r;
        acc[c][r] += red[0][l][idx] + red[1][l][idx] + red[2][l][idx];
      }
    // Pcat -> bf16 LDS A-tile [16][168]; denom = kcol 159 (f32 exact)
    #pragma unroll
    for (int c = 0; c < 10; ++c)
      #pragma unroll
      for (int r = 0; r < 4; ++r)
        pA[(q * 4 + r) * 168 + c * 16 + rl] = f2bf(acc[c][r]);
    if (rl == 15) {
      #pragma unroll
      for (int r = 0; r < 4; ++r) denomLDS[q * 4 + r] = acc[9][r];
    }
  }
  __syncthreads();

  // second GEMM: 16x160 @ 160x80, parallel across waves by output col-tile
  for (int nt = wid; nt < 5; nt += 4) {
    short8 af2[5];
    #pragma unroll
    for (int ks = 0; ks < 5; ++ks)
      af2[ks] = *(const short8*)&pA[rl * 168 + ks * 32 + q * 8];
    f32x4 acc2 = (f32x4){0.f, 0.f, 0.f, 0.f};
    #pragma unroll
    for (int ks = 0; ks < 5; ++ks)
      acc2 = __builtin_amdgcn_mfma_f32_16x16x32_bf16(
          af2[ks],
          *(const short8*)&WoutT[(size_t)(nt * 16 + rl) * KP_ + ks * 32 + q * 8],
          acc2, 0, 0, 0);
    #pragma unroll
    for (int r = 0; r < 4; ++r) {
      const float dv = denomLDS[q * 4 + r];
      const float invr = dv > 0.f ? 1.f / dv : 0.f;
      const size_t ob = ((size_t)bb * N_ + n0 + q * 4 + r) * FO_;
      out[ob + nt * 16 + rl] = acc2[r] * invr;
    }
  }
}

extern "C" void kernel_launch(void* const* d_in, const int* in_sizes, int n_in,
                              void* d_out, int out_size, void* d_ws, size_t ws_size,
                              hipStream_t stream) {
  const float* h    = (const float*)d_in[0];
  const int*   adj  = (const int*)d_in[1];
  const float* Ws   = (const float*)d_in[2];
  const float* aa   = (const float*)d_in[3];
  const float* Wout = (const float*)d_in[4];
  const float* aout = (const float*)d_in[5];

  char* ws = (char*)d_ws;
  unsigned short* whT   = (unsigned short*)(ws + 0);         // 6,291,456
  float* e1h            = (float*)(ws + 6291456);            //   196,608
  float* e2h            = (float*)(ws + 6488064);            //   196,608
  u64*   mk             = (u64*)  (ws + 6684672);            // 1,048,576
  unsigned short* catT  = (unsigned short*)(ws + 7733248);   // 5,242,880
  unsigned short* WoutT = (unsigned short*)(ws + 12976128);  //    30,720
  float* wv1            = (float*)(ws + 13008896);           //     1,024
  float* wv2            = (float*)(ws + 13009920);           //     1,024
  float* e1p            = (float*)(ws + 13010944);           //   196,608
  float* e2p            = (float*)(ws + 13207552);           //   196,608

  hipLaunchKernelGGL(k0_maskprep, dim3(2064), dim3(256), 0, stream,
                     adj, Wout, aout, mk, WoutT, wv1, wv2);
  hipLaunchKernelGGL(k1_mfma, dim3(768), dim3(256), 0, stream,
                     h, Ws, aa, whT, e1h, e2h);
  hipLaunchKernelGGL(k3s, dim3(768), dim3(256), 0, stream,
                     whT, e1h, e2h, mk, wv1, wv2, catT, e1p, e2p);
  hipLaunchKernelGGL(kC, dim3(1024), dim3(256), 0, stream,
                     catT, WoutT, e1p, e2p, mk, (float*)d_out);
}

// Round 13
// 73.832 us; speedup vs baseline: 1.0626x; 1.0626x over previous
//
#include <hip/hip_runtime.h>
#include <stdint.h>

typedef unsigned long long u64;
typedef __attribute__((ext_vector_type(8))) short short8;   // 8 x bf16 (4 VGPR)
typedef __attribute__((ext_vector_type(4))) float f32x4;    // MFMA C/D frag

#define B_ 32
#define N_ 512
#define FIN_ 80
#define FH_ 50
#define FO_ 80
#define CAT_ 150
#define KP_ 160   // padded K for layer-2 GEMM
#define NP_ 96    // padded N for layer-2 (80 cols + 15 zero + 1 ones@95)

__device__ inline unsigned short f2bf(float f) {  // RNE float -> bf16 bits
  unsigned u = __float_as_uint(f);
  u += 0x7fffu + ((u >> 16) & 1u);
  return (unsigned short)(u >> 16);
}

__device__ inline unsigned nib4(int4 v) {
  return (v.x != 0 ? 1u : 0u) | (v.y != 0 ? 2u : 0u) |
         (v.z != 0 ? 4u : 0u) | (v.w != 0 ? 8u : 0u);
}

// A-fragment builder: p = exp(min(lrelu(e1+e2),60)) masked, bf16
__device__ inline short8 build_af(const float* e2s, float e1r, u64 word,
                                  int jb, int shift) {
  short8 af;
  unsigned b0 = (unsigned)(word >> shift) & 0xffu;
  float4 va = *(const float4*)&e2s[jb];
  float4 vb = *(const float4*)&e2s[jb + 4];
  float ev[8] = {va.x, va.y, va.z, va.w, vb.x, vb.y, vb.z, vb.w};
  #pragma unroll
  for (int e = 0; e < 8; ++e) {
    float sv = e1r + ev[e];
    sv = fmaxf(sv, 0.2f * sv);
    sv = fminf(sv, 60.f);
    float arg = ((b0 >> e) & 1u) ? sv : -1e30f;
    af[e] = (short)f2bf(__expf(arg));
  }
  return af;
}

// ---------- kA: 0..2047 mask | 2048..2062 WoutT | 2063 wv | 2064..2831 k1-MFMA ----
__global__ __launch_bounds__(256) void kA(const float* __restrict__ h,
                                          const int* __restrict__ adj,
                                          const float* __restrict__ Ws,
                                          const float* __restrict__ attn_a,
                                          const float* __restrict__ Wout,
                                          const float* __restrict__ a_out,
                                          unsigned short* __restrict__ whT,
                                          float* __restrict__ e1h,
                                          float* __restrict__ e2h,
                                          u64* __restrict__ maskw,
                                          unsigned short* __restrict__ WoutT,
                                          float* __restrict__ wv1,
                                          float* __restrict__ wv2) {
  __shared__ __align__(16) unsigned short un[64 * 104];     // h bf16; tbT[64][72]; mask sm
  __shared__ __align__(16) unsigned short bstage[12 * 512]; // Ws B-frags
  const int t = threadIdx.x;
  const int bid = blockIdx.x;

  if (bid < 2048) {  // ---- mask: 8 rows/block (R9-proven pattern) ----
    unsigned short* sm = un;
    const int r = t >> 5, s = t & 31;
    const int row = bid * 8 + r;
    const int4* src = (const int4*)(adj + (size_t)row * N_ + s * 16);
    int4 v0 = src[0], v1 = src[1], v2 = src[2], v3 = src[3];  // 4 indep 16B loads
    unsigned m = nib4(v0) | (nib4(v1) << 4) | (nib4(v2) << 8) | (nib4(v3) << 12);
    sm[t] = (unsigned short)m;
    __syncthreads();
    if (t < 64) {
      const int rr = t >> 3, w = t & 7;
      const unsigned short* p = &sm[rr * 32 + w * 4];
      u64 mm = (u64)p[0] | ((u64)p[1] << 16) | ((u64)p[2] << 32) | ((u64)p[3] << 48);
      maskw[(size_t)(bid * 8 + rr) * 8 + w] = mm;
    }
    return;
  }
  if (bid < 2063) {  // ---- WoutT[col 96][k 160] bf16: 1 uint2/thread ----
    const int i = (bid - 2048) * 256 + t;
    const int base = i * 4;
    const int col = base / KP_, k0 = base % KP_;
    unsigned short pk[4];
    #pragma unroll
    for (int e = 0; e < 4; ++e) {
      const int k = k0 + e;
      pk[e] = (col < FO_ && k < CAT_) ? f2bf(Wout[(size_t)k * FO_ + col]) : 0;
    }
    uint2 o;
    o.x = (unsigned)pk[0] | ((unsigned)pk[1] << 16);
    o.y = (unsigned)pk[2] | ((unsigned)pk[3] << 16);
    ((uint2*)WoutT)[i] = o;
    return;
  }
  if (bid == 2063) {  // ---- wv1/wv2[k] = Wout[k][:] . a_out halves ----
    if (t < CAT_) {
      const float4* wr = (const float4*)(Wout + (size_t)t * FO_);
      const float4* a1 = (const float4*)a_out;
      const float4* a2 = (const float4*)(a_out + FO_);
      float p1 = 0.f, p2 = 0.f;
      #pragma unroll
      for (int i = 0; i < 20; ++i) {
        float4 v = wr[i], x1 = a1[i], x2 = a2[i];
        p1 += v.x * x1.x + v.y * x1.y + v.z * x1.z + v.w * x1.w;
        p2 += v.x * x2.x + v.y * x2.y + v.z * x2.z + v.w * x2.w;
      }
      wv1[t] = p1; wv2[t] = p2;
    }
    return;
  }

  // ---- k1: Wh via MFMA; e1h/e2h from MFMA accs; whT bf16 [col64][j512] ----
  int x = bid - 2064;
  const int rt = x & 7; x >>= 3;
  const int bb = x & 31; x >>= 5;
  const int hh = x;
  const int n0 = rt * 64;
  const float* hblk = h + ((size_t)bb * N_ + n0) * FIN_;
  const float* wsrc = Ws + (size_t)hh * FIN_ * FH_;

  for (int idx = t; idx < 64 * 13; idx += 256) {  // h tile bf16 [64][104]
    const int row = idx / 13, k0 = (idx - row * 13) * 8;
    short8 v8;
    if (k0 < FIN_) {
      float4 a = *(const float4*)(hblk + row * FIN_ + k0);
      float4 b = *(const float4*)(hblk + row * FIN_ + k0 + 4);
      v8[0] = (short)f2bf(a.x); v8[1] = (short)f2bf(a.y);
      v8[2] = (short)f2bf(a.z); v8[3] = (short)f2bf(a.w);
      v8[4] = (short)f2bf(b.x); v8[5] = (short)f2bf(b.y);
      v8[6] = (short)f2bf(b.z); v8[7] = (short)f2bf(b.w);
    } else {
      #pragma unroll
      for (int e = 0; e < 8; ++e) v8[e] = 0;
    }
    *(short8*)&un[row * 104 + k0] = v8;
  }
  for (int idx = t; idx < 768; idx += 256) {  // B-frags from Ws (L2-cached)
    const int f = idx >> 6, lf = idx & 63;
    const int ks = f >> 2, nt = f & 3;
    const int kb = ks * 32 + (lf >> 4) * 8, n = nt * 16 + (lf & 15);
    short8 v8;
    #pragma unroll
    for (int e = 0; e < 8; ++e) {
      const int k = kb + e;
      v8[e] = (k < FIN_ && n < FH_) ? (short)f2bf(wsrc[k * FH_ + n]) : (short)0;
    }
    *(short8*)&bstage[idx * 8] = v8;
  }
  __syncthreads();

  const int l = t & 63, wv = t >> 6, q = l >> 4, rl = l & 15;
  f32x4 acc[4];
  {
    short8 af[3];
    #pragma unroll
    for (int ks = 0; ks < 3; ++ks)
      af[ks] = *(const short8*)&un[(wv * 16 + rl) * 104 + ks * 32 + q * 8];
    #pragma unroll
    for (int nt = 0; nt < 4; ++nt) acc[nt] = (f32x4){0.f, 0.f, 0.f, 0.f};
    #pragma unroll
    for (int ks = 0; ks < 3; ++ks)
      #pragma unroll
      for (int nt = 0; nt < 4; ++nt)
        acc[nt] = __builtin_amdgcn_mfma_f32_16x16x32_bf16(
            af[ks], *(const short8*)&bstage[((ks * 4 + nt) * 64 + l) * 8], acc[nt], 0, 0, 0);
  }
  {  // e1/e2 from f32 accumulators: e[j] = sum_col Wh[j][col]*a[col]
    float a1v[4], a2v[4];
    #pragma unroll
    for (int c = 0; c < 4; ++c) {
      const int col = c * 16 + rl;
      a1v[c] = (col < FH_) ? attn_a[hh * 2 * FH_ + col] : 0.f;
      a2v[c] = (col < FH_) ? attn_a[hh * 2 * FH_ + FH_ + col] : 0.f;
    }
    #pragma unroll
    for (int r = 0; r < 4; ++r) {
      float p1 = acc[0][r] * a1v[0] + acc[1][r] * a1v[1] +
                 acc[2][r] * a1v[2] + acc[3][r] * a1v[3];
      float p2 = acc[0][r] * a2v[0] + acc[1][r] * a2v[1] +
                 acc[2][r] * a2v[2] + acc[3][r] * a2v[3];
      p1 += __shfl_xor(p1, 1); p1 += __shfl_xor(p1, 2);
      p1 += __shfl_xor(p1, 4); p1 += __shfl_xor(p1, 8);
      p2 += __shfl_xor(p2, 1); p2 += __shfl_xor(p2, 2);
      p2 += __shfl_xor(p2, 4); p2 += __shfl_xor(p2, 8);
      if (rl == 0) {
        size_t o = ((size_t)hh * B_ + bb) * N_ + n0 + wv * 16 + q * 4 + r;
        e1h[o] = p1; e2h[o] = p2;
      }
    }
  }
  __syncthreads();   // un reads done -> reuse as tbT
  unsigned short* tbT = un;  // [col][j], stride 72
  #pragma unroll
  for (int nt = 0; nt < 4; ++nt)
    #pragma unroll
    for (int r2 = 0; r2 < 4; ++r2)
      tbT[(nt * 16 + rl) * 72 + wv * 16 + q * 4 + r2] = f2bf(acc[nt][r2]);
  __syncthreads();
  {  // emit whT[col][j] coalesced; col 63 = ones (layer-1 denominator)
    const int col = t & 63, half = t >> 6;
    uint4 o0 = *(const uint4*)&tbT[col * 72 + half * 16];
    uint4 o1 = *(const uint4*)&tbT[col * 72 + half * 16 + 8];
    if (col == 63) {
      o0.x = o0.y = o0.z = o0.w = 0x3f803f80u;
      o1 = o0;
    }
    unsigned short* dst = whT + (((size_t)hh * B_ + bb) * 64 + col) * 512 + n0 + half * 16;
    *(uint4*)dst = o0;
    *(uint4*)(dst + 8) = o1;
  }
}

// ---------- k3s: layer-1 attention, 16-row blocks, 4-wave j-split (R9 verbatim) ----
__global__ __launch_bounds__(256) void k3s(const unsigned short* __restrict__ whT,
                                           const float* __restrict__ e1,
                                           const float* __restrict__ e2,
                                           const u64* __restrict__ maskw,
                                           const float* __restrict__ wv1,
                                           const float* __restrict__ wv2,
                                           unsigned short* __restrict__ catbf,
                                           float* __restrict__ e1p,
                                           float* __restrict__ e2p) {
  __shared__ __align__(16) float e2s[N_];
  __shared__ __align__(16) float red[4][64][17];
  int x = (int)((blockIdx.x & 7) * 384 + (blockIdx.x >> 3));  // bijective (3072%8==0)
  const int hh = x >> 10;
  const int bb = (x >> 5) & 31;
  const int rg = x & 31;
  const int n0 = rg * 16;
  const int t = threadIdx.x;
  const int l = t & 63, wid = t >> 6;
  const int q = l >> 4, rl = l & 15;

  const float* e2pp = e2 + ((size_t)hh * B_ + bb) * N_;
  for (int i = t; i < N_ / 4; i += 256) ((float4*)e2s)[i] = ((const float4*)e2pp)[i];
  __syncthreads();

  const int row = n0 + rl;
  const float e1r = e1[((size_t)hh * B_ + bb) * N_ + row];
  const u64* mr = maskw + ((size_t)bb * N_ + row) * 8;

  f32x4 acc[4];
  #pragma unroll
  for (int c = 0; c < 4; ++c) acc[c] = (f32x4){0.f, 0.f, 0.f, 0.f};
  const unsigned short* wb = whT + ((size_t)hh * B_ + bb) * 64 * 512;

  #pragma unroll
  for (int tts = 0; tts < 2; ++tts) {
    const int tt = wid * 2 + tts;
    short8 bf[4][2];
    #pragma unroll
    for (int c = 0; c < 4; ++c) {
      const unsigned short* bp = wb + (size_t)(c * 16 + rl) * 512 + tt * 64 + q * 8;
      bf[c][0] = *(const short8*)bp;
      bf[c][1] = *(const short8*)(bp + 32);
    }
    u64 word = mr[tt];
    short8 af0 = build_af(e2s, e1r, word, tt * 64 + q * 8, q * 8);
    short8 af1 = build_af(e2s, e1r, word, tt * 64 + 32 + q * 8, 32 + q * 8);
    #pragma unroll
    for (int c = 0; c < 4; ++c) {
      acc[c] = __builtin_amdgcn_mfma_f32_16x16x32_bf16(af0, bf[c][0], acc[c], 0, 0, 0);
      acc[c] = __builtin_amdgcn_mfma_f32_16x16x32_bf16(af1, bf[c][1], acc[c], 0, 0, 0);
    }
  }

  #pragma unroll
  for (int c = 0; c < 4; ++c)
    #pragma unroll
    for (int r = 0; r < 4; ++r) red[wid][l][c * 4 + r] = acc[c][r];
  __syncthreads();

  if (wid == 0) {
    #pragma unroll
    for (int c = 0; c < 4; ++c)
      #pragma unroll
      for (int r = 0; r < 4; ++r)
        acc[c][r] = red[0][l][c * 4 + r] + red[1][l][c * 4 + r] +
                    red[2][l][c * 4 + r] + red[3][l][c * 4 + r];
    float w1c[4], w2c[4];
    #pragma unroll
    for (int c = 0; c < 4; ++c) {
      const int col = c * 16 + rl;
      w1c[c] = (col < FH_) ? wv1[hh * FH_ + col] : 0.f;
      w2c[c] = (col < FH_) ? wv2[hh * FH_ + col] : 0.f;
    }
    #pragma unroll
    for (int r = 0; r < 4; ++r) {
      float srow = __shfl(acc[3][r], (q << 4) | 15);  // col 63 = denom (ones col)
      float invr = srow > 0.f ? 1.f / srow : 0.f;
      const size_t grow = (size_t)bb * N_ + n0 + q * 4 + r;
      float p1 = 0.f, p2 = 0.f;
      #pragma unroll
      for (int c = 0; c < 4; ++c) {
        const int col = c * 16 + rl;
        if (col < FH_) {
          float v = acc[c][r] * invr;
          v = v > 0.f ? v : __expf(v) - 1.f;  // ELU
          catbf[grow * KP_ + hh * FH_ + col] = f2bf(v);
          p1 += v * w1c[c];
          p2 += v * w2c[c];
        }
      }
      p1 += __shfl_xor(p1, 1); p1 += __shfl_xor(p1, 2);
      p1 += __shfl_xor(p1, 4); p1 += __shfl_xor(p1, 8);
      p2 += __shfl_xor(p2, 1); p2 += __shfl_xor(p2, 2);
      p2 += __shfl_xor(p2, 4); p2 += __shfl_xor(p2, 8);
      if (rl == 0) {
        e1p[(size_t)hh * (B_ * N_) + grow] = p1;
        e2p[(size_t)hh * (B_ * N_) + grow] = p2;
      }
    }
  }
  if (hh == 2 && t < 16) {  // zero-pad K cols 150..159 for this block's 16 rows
    const size_t grow = (size_t)bb * N_ + n0 + t;
    unsigned* zp = (unsigned*)&catbf[grow * KP_ + CAT_];
    #pragma unroll
    for (int i = 0; i < 5; ++i) zp[i] = 0u;
  }
}

// ---------- k4: Wh2 = catbf @ WoutT via MFMA (cols 0..79); fill 80..95 (R9) --------
__global__ __launch_bounds__(256) void k4_gemm2(const unsigned short* __restrict__ catbf,
                                                const unsigned short* __restrict__ WoutT,
                                                unsigned short* __restrict__ wh2T) {
  const int t = threadIdx.x, l = t & 63, wid = t >> 6;
  const int q = l >> 4, rl = l & 15;
  const int blk = blockIdx.x;
  const int jbase = blk * 64 + wid * 16;
  f32x4 acc[5];
  #pragma unroll
  for (int nt = 0; nt < 5; ++nt) acc[nt] = (f32x4){0.f, 0.f, 0.f, 0.f};
  const unsigned short* ap = catbf + (size_t)(jbase + rl) * KP_ + q * 8;
  #pragma unroll
  for (int kk = 0; kk < 5; ++kk) {
    short8 a = *(const short8*)(ap + kk * 32);
    #pragma unroll
    for (int nt = 0; nt < 5; ++nt) {
      short8 b = *(const short8*)&WoutT[(size_t)(nt * 16 + rl) * KP_ + kk * 32 + q * 8];
      acc[nt] = __builtin_amdgcn_mfma_f32_16x16x32_bf16(a, b, acc[nt], 0, 0, 0);
    }
  }
  const int bb = blk >> 3, jt = blk & 7;
  const int j0 = jt * 64 + wid * 16 + q * 4;
  #pragma unroll
  for (int nt = 0; nt < 5; ++nt) {
    const int col = nt * 16 + rl;
    unsigned short pk[4];
    #pragma unroll
    for (int r = 0; r < 4; ++r) pk[r] = f2bf(acc[nt][r]);
    uint2 o;
    o.x = (unsigned)pk[0] | ((unsigned)pk[1] << 16);
    o.y = (unsigned)pk[2] | ((unsigned)pk[3] << 16);
    *(uint2*)&wh2T[((size_t)bb * NP_ + col) * 512 + j0] = o;
  }
  {
    const int col = 80 + (t >> 4), jq = (t & 15) * 4;
    unsigned fill = (col == 95) ? 0x3f803f80u : 0u;
    uint2 o; o.x = fill; o.y = fill;
    *(uint2*)&wh2T[((size_t)bb * NP_ + col) * 512 + jt * 64 + jq] = o;
  }
}

// ---------- k5: layer-2 attention, 16-row blocks, 4-wave j-split (R9 verbatim) -----
__global__ __launch_bounds__(256) void k5_attn2(const unsigned short* __restrict__ wh2T,
                                                const float* __restrict__ e1p,
                                                const float* __restrict__ e2p,
                                                const u64* __restrict__ maskw,
                                                float* __restrict__ out) {
  __shared__ __align__(16) float e2s[N_];
  __shared__ __align__(16) float red[4][64][25];
  int x = (int)((blockIdx.x & 7) * 128 + (blockIdx.x >> 3));
  const int rg = x & 31;
  const int bb = x >> 5;
  const int n0 = rg * 16;
  const int t = threadIdx.x;
  const int l = t & 63, wid = t >> 6;
  const int q = l >> 4, rl = l & 15;

  for (int i = t; i < N_ / 4; i += 256) {
    float4 v0 = ((const float4*)(e2p))[(size_t)bb * 128 + i];
    float4 v1 = ((const float4*)(e2p + B_ * N_))[(size_t)bb * 128 + i];
    float4 v2 = ((const float4*)(e2p + 2 * B_ * N_))[(size_t)bb * 128 + i];
    float4 s;
    s.x = v0.x + v1.x + v2.x; s.y = v0.y + v1.y + v2.y;
    s.z = v0.z + v1.z + v2.z; s.w = v0.w + v1.w + v2.w;
    ((float4*)e2s)[i] = s;
  }
  __syncthreads();

  const int row = n0 + rl;
  const size_t gr = (size_t)bb * N_ + row;
  const float e1r = e1p[gr] + e1p[B_ * N_ + gr] + e1p[2 * B_ * N_ + gr];
  const u64* mr = maskw + gr * 8;

  f32x4 acc[6];
  #pragma unroll
  for (int c = 0; c < 6; ++c) acc[c] = (f32x4){0.f, 0.f, 0.f, 0.f};
  const unsigned short* wb = wh2T + (size_t)bb * NP_ * 512;

  #pragma unroll
  for (int tts = 0; tts < 2; ++tts) {
    const int tt = wid * 2 + tts;
    short8 bf[6][2];
    #pragma unroll
    for (int c = 0; c < 6; ++c) {
      const unsigned short* bp = wb + (size_t)(c * 16 + rl) * 512 + tt * 64 + q * 8;
      bf[c][0] = *(const short8*)bp;
      bf[c][1] = *(const short8*)(bp + 32);
    }
    u64 word = mr[tt];
    short8 af0 = build_af(e2s, e1r, word, tt * 64 + q * 8, q * 8);
    short8 af1 = build_af(e2s, e1r, word, tt * 64 + 32 + q * 8, 32 + q * 8);
    #pragma unroll
    for (int c = 0; c < 6; ++c) {
      acc[c] = __builtin_amdgcn_mfma_f32_16x16x32_bf16(af0, bf[c][0], acc[c], 0, 0, 0);
      acc[c] = __builtin_amdgcn_mfma_f32_16x16x32_bf16(af1, bf[c][1], acc[c], 0, 0, 0);
    }
  }

  #pragma unroll
  for (int c = 0; c < 6; ++c)
    #pragma unroll
    for (int r = 0; r < 4; ++r) red[wid][l][c * 4 + r] = acc[c][r];
  __syncthreads();

  if (wid == 0) {
    #pragma unroll
    for (int c = 0; c < 6; ++c)
      #pragma unroll
      for (int r = 0; r < 4; ++r)
        acc[c][r] = red[0][l][c * 4 + r] + red[1][l][c * 4 + r] +
                    red[2][l][c * 4 + r] + red[3][l][c * 4 + r];
    const size_t orow0 = (size_t)bb * N_ + n0;
    #pragma unroll
    for (int r = 0; r < 4; ++r) {
      float srow = __shfl(acc[5][r], (q << 4) | 15);  // col 95 = denom
      float invr = srow > 0.f ? 1.f / srow : 0.f;
      const size_t ob = (orow0 + q * 4 + r) * FO_;
      #pragma unroll
      for (int c = 0; c < 5; ++c) out[ob + c * 16 + rl] = acc[c][r] * invr;
    }
  }
}

extern "C" void kernel_launch(void* const* d_in, const int* in_sizes, int n_in,
                              void* d_out, int out_size, void* d_ws, size_t ws_size,
                              hipStream_t stream) {
  const float* h    = (const float*)d_in[0];
  const int*   adj  = (const int*)d_in[1];
  const float* Ws   = (const float*)d_in[2];
  const float* aa   = (const float*)d_in[3];
  const float* Wout = (const float*)d_in[4];
  const float* aout = (const float*)d_in[5];

  char* ws = (char*)d_ws;
  unsigned short* whT   = (unsigned short*)(ws + 0);         // 6,291,456
  float* e1h            = (float*)(ws + 6291456);            //   196,608
  float* e2h            = (float*)(ws + 6488064);            //   196,608
  u64*   mk             = (u64*)  (ws + 6684672);            // 1,048,576
  unsigned short* catbf = (unsigned short*)(ws + 7733248);   // 5,242,880
  unsigned short* WoutT = (unsigned short*)(ws + 12976128);  //    30,720
  float* wv1            = (float*)(ws + 13008896);           //     1,024
  float* wv2            = (float*)(ws + 13009920);           //     1,024
  float* e1p            = (float*)(ws + 13010944);           //   196,608
  float* e2p            = (float*)(ws + 13207552);           //   196,608
  unsigned short* wh2T  = (unsigned short*)(ws + 13404160);  // 3,145,728

  hipLaunchKernelGGL(kA, dim3(2832), dim3(256), 0, stream,
                     h, adj, Ws, aa, Wout, aout, whT, e1h, e2h, mk, WoutT, wv1, wv2);
  hipLaunchKernelGGL(k3s, dim3(3072), dim3(256), 0, stream,
                     whT, e1h, e2h, mk, wv1, wv2, catbf, e1p, e2p);
  hipLaunchKernelGGL(k4_gemm2, dim3(256), dim3(256), 0, stream, catbf, WoutT, wh2T);
  hipLaunchKernelGGL(k5_attn2, dim3(1024), dim3(256), 0, stream,
                     wh2T, e1p, e2p, mk, (float*)d_out);
}

// Round 14
// 72.014 us; speedup vs baseline: 1.0894x; 1.0253x over previous
//
#include <hip/hip_runtime.h>
#include <stdint.h>

typedef unsigned long long u64;
typedef __attribute__((ext_vector_type(8))) short short8;   // 8 x bf16 (4 VGPR)
typedef __attribute__((ext_vector_type(4))) float f32x4;    // MFMA C/D frag

#define B_ 32
#define N_ 512
#define FIN_ 80
#define FH_ 50
#define FO_ 80
#define CAT_ 150
#define KP_ 160   // padded K for layer-2 GEMM
#define NP_ 96    // padded N for layer-2 (80 cols + 15 zero + 1 ones@95)

__device__ inline unsigned short f2bf(float f) {  // RNE float -> bf16 bits
  unsigned u = __float_as_uint(f);
  u += 0x7fffu + ((u >> 16) & 1u);
  return (unsigned short)(u >> 16);
}

__device__ inline unsigned nib4(int4 v) {
  return (v.x != 0 ? 1u : 0u) | (v.y != 0 ? 2u : 0u) |
         (v.z != 0 ? 4u : 0u) | (v.w != 0 ? 8u : 0u);
}

// A-fragment builder: p = exp(min(lrelu(e1+e2),60)) masked, bf16
__device__ inline short8 build_af(const float* e2s, float e1r, u64 word,
                                  int jb, int shift) {
  short8 af;
  unsigned b0 = (unsigned)(word >> shift) & 0xffu;
  float4 va = *(const float4*)&e2s[jb];
  float4 vb = *(const float4*)&e2s[jb + 4];
  float ev[8] = {va.x, va.y, va.z, va.w, vb.x, vb.y, vb.z, vb.w};
  #pragma unroll
  for (int e = 0; e < 8; ++e) {
    float sv = e1r + ev[e];
    sv = fmaxf(sv, 0.2f * sv);
    sv = fminf(sv, 60.f);
    float arg = ((b0 >> e) & 1u) ? sv : -1e30f;
    af[e] = (short)f2bf(__expf(arg));
  }
  return af;
}

// ---------- K0: bids 0..2047 = mask (8 rows each); 2048+ = parallel weight prep ----
__global__ __launch_bounds__(256) void k0_maskprep(const int* __restrict__ adj,
                                                   const float* __restrict__ Ws,
                                                   const float* __restrict__ attn_a,
                                                   const float* __restrict__ Wout,
                                                   const float* __restrict__ a_out,
                                                   u64* __restrict__ maskw,
                                                   unsigned short* __restrict__ WsT,
                                                   float* __restrict__ wa1g,
                                                   float* __restrict__ wa2g,
                                                   unsigned short* __restrict__ WoutT,
                                                   float* __restrict__ wv1,
                                                   float* __restrict__ wv2) {
  __shared__ unsigned short sm[256];
  const int t = threadIdx.x;
  const int bid = blockIdx.x;

  if (bid < 2048) {  // ---- mask: 8 rows/block, thread = (row r=t>>5, seg s=t&31) ----
    const int r = t >> 5, s = t & 31;
    const int row = bid * 8 + r;
    const int4* src = (const int4*)(adj + (size_t)row * N_ + s * 16);
    int4 v0 = src[0], v1 = src[1], v2 = src[2], v3 = src[3];  // 4 indep 16B loads
    unsigned m = nib4(v0) | (nib4(v1) << 4) | (nib4(v2) << 8) | (nib4(v3) << 12);
    sm[t] = (unsigned short)m;
    __syncthreads();
    if (t < 64) {
      const int rr = t >> 3, w = t & 7;
      const unsigned short* p = &sm[rr * 32 + w * 4];
      u64 mm = (u64)p[0] | ((u64)p[1] << 16) | ((u64)p[2] << 32) | ((u64)p[3] << 48);
      maskw[(size_t)(bid * 8 + rr) * 8 + w] = mm;  // contiguous 512B per block
    }
    return;
  }

  const int pb = bid - 2048;
  if (pb < 15) {  // ---- WoutT[col 96][k 160] bf16: 3840 uint2 entries, 1/thread ----
    const int i = pb * 256 + t;
    const int base = i * 4;
    const int col = base / KP_, k0 = base % KP_;
    unsigned short pk[4];
    #pragma unroll
    for (int e = 0; e < 4; ++e) {
      const int k = k0 + e;
      pk[e] = (col < FO_ && k < CAT_) ? f2bf(Wout[(size_t)k * FO_ + col]) : 0;
    }
    uint2 o;
    o.x = (unsigned)pk[0] | ((unsigned)pk[1] << 16);
    o.y = (unsigned)pk[2] | ((unsigned)pk[3] << 16);
    ((uint2*)WoutT)[i] = o;
  } else if (pb < 24) {  // ---- WsT pre-swizzled B-frags: 2304 short8 entries ----
    const int idx = (pb - 15) * 256 + t;
    const int hh = idx / 768, rem = idx - hh * 768;
    const int f = rem >> 6, lf = rem & 63;
    const int ks = f >> 2, nt = f & 3;
    const int kb = ks * 32 + (lf >> 4) * 8, n = nt * 16 + (lf & 15);
    const float* wsrc = Ws + (size_t)hh * FIN_ * FH_;
    short8 v8;
    #pragma unroll
    for (int e = 0; e < 8; ++e) {
      const int k = kb + e;
      v8[e] = (k < FIN_ && n < FH_) ? (short)f2bf(wsrc[k * FH_ + n]) : (short)0;
    }
    *(short8*)&WsT[(size_t)idx * 8] = v8;
  } else if (pb == 24) {  // ---- wa1/wa2[hh][k] = Ws[hh][k][:] . a halves (f32) ----
    if (t < 3 * FIN_) {
      const int hh = t / FIN_, k = t - hh * FIN_;
      const float* wr = Ws + ((size_t)hh * FIN_ + k) * FH_;
      const float* a1 = attn_a + hh * 2 * FH_;
      float s1 = 0.f, s2 = 0.f;
      #pragma unroll 10
      for (int c = 0; c < FH_; ++c) { s1 += wr[c] * a1[c]; s2 += wr[c] * a1[FH_ + c]; }
      wa1g[t] = s1; wa2g[t] = s2;
    }
  } else {  // ---- wv1/wv2[k] = Wout[k][:] . a_out halves (f32) ----
    if (t < CAT_) {
      const float4* wr = (const float4*)(Wout + (size_t)t * FO_);
      const float4* a1 = (const float4*)a_out;
      const float4* a2 = (const float4*)(a_out + FO_);
      float p1 = 0.f, p2 = 0.f;
      #pragma unroll
      for (int i = 0; i < 20; ++i) {
        float4 v = wr[i], x1 = a1[i], x2 = a2[i];
        p1 += v.x * x1.x + v.y * x1.y + v.z * x1.z + v.w * x1.w;
        p2 += v.x * x2.x + v.y * x2.y + v.z * x2.z + v.w * x2.w;
      }
      wv1[t] = p1; wv2[t] = p2;
    }
  }
}

// ---------- K1: Wh via MFMA; e1h/e2h f32-exact; whT bf16 [col64][j512], col63=1 ----
__global__ __launch_bounds__(256) void k1_mfma(const float* __restrict__ h,
                                               const unsigned short* __restrict__ WsT,
                                               const float* __restrict__ wa1g,
                                               const float* __restrict__ wa2g,
                                               unsigned short* __restrict__ whT,
                                               float* __restrict__ e1h,
                                               float* __restrict__ e2h) {
  __shared__ __align__(16) unsigned short un[64 * 104];  // hsb, then reused as tbT[64][72]
  const int t = threadIdx.x;
  int x = blockIdx.x;
  const int rt = x & 7; x >>= 3;
  const int bb = x & 31; x >>= 5;
  const int hh = x;
  const int n0 = rt * 64;
  const float* hblk = h + ((size_t)bb * N_ + n0) * FIN_;

  // stage h tile as bf16 [64][104] (zero-pad k>=80)
  for (int idx = t; idx < 64 * 13; idx += 256) {
    const int row = idx / 13, k0 = (idx - row * 13) * 8;
    short8 v8;
    if (k0 < FIN_) {
      float4 a = *(const float4*)(hblk + row * FIN_ + k0);
      float4 b = *(const float4*)(hblk + row * FIN_ + k0 + 4);
      v8[0] = (short)f2bf(a.x); v8[1] = (short)f2bf(a.y);
      v8[2] = (short)f2bf(a.z); v8[3] = (short)f2bf(a.w);
      v8[4] = (short)f2bf(b.x); v8[5] = (short)f2bf(b.y);
      v8[6] = (short)f2bf(b.z); v8[7] = (short)f2bf(b.w);
    } else {
      #pragma unroll
      for (int e = 0; e < 8; ++e) v8[e] = 0;
    }
    *(short8*)&un[row * 104 + k0] = v8;
  }
  __syncthreads();

  // e1/e2 exact f32: thread = (row r, k-quarter cq); reads h + wa from global (L2)
  {
    const int r = t >> 2, cq = t & 3;
    const float* hr = hblk + r * FIN_ + cq * 20;
    const float4* w1 = (const float4*)(wa1g + hh * FIN_ + cq * 20);
    const float4* w2 = (const float4*)(wa2g + hh * FIN_ + cq * 20);
    float s1 = 0.f, s2 = 0.f;
    #pragma unroll
    for (int i = 0; i < 5; ++i) {
      float4 hv = *(const float4*)(hr + i * 4);
      float4 a = w1[i], b = w2[i];
      s1 += hv.x * a.x + hv.y * a.y + hv.z * a.z + hv.w * a.w;
      s2 += hv.x * b.x + hv.y * b.y + hv.z * b.z + hv.w * b.w;
    }
    s1 += __shfl_xor(s1, 1); s1 += __shfl_xor(s1, 2);
    s2 += __shfl_xor(s2, 1); s2 += __shfl_xor(s2, 2);
    if (cq == 0) {
      size_t o = ((size_t)hh * B_ + bb) * N_ + n0 + r;
      e1h[o] = s1; e2h[o] = s2;
    }
  }

  // MFMA: per wave 16 rows x 64 cols, K=96 (3 steps); B-frags from global WsT
  const int l = t & 63, wv = t >> 6, q = l >> 4, rl = l & 15;
  f32x4 acc[4];
  {
    short8 af[3];
    #pragma unroll
    for (int ks = 0; ks < 3; ++ks)
      af[ks] = *(const short8*)&un[(wv * 16 + rl) * 104 + ks * 32 + q * 8];
    #pragma unroll
    for (int nt = 0; nt < 4; ++nt) acc[nt] = (f32x4){0.f, 0.f, 0.f, 0.f};
    const unsigned short* wsb = WsT + (size_t)hh * 12 * 512;
    #pragma unroll
    for (int ks = 0; ks < 3; ++ks)
      #pragma unroll
      for (int nt = 0; nt < 4; ++nt)
        acc[nt] = __builtin_amdgcn_mfma_f32_16x16x32_bf16(
            af[ks], *(const short8*)&wsb[((ks * 4 + nt) * 64 + l) * 8], acc[nt], 0, 0, 0);
  }
  __syncthreads();   // all af reads done -> safe to reuse `un` as tbT
  unsigned short* tbT = un;  // [col][j], stride 72
  #pragma unroll
  for (int nt = 0; nt < 4; ++nt)
    #pragma unroll
    for (int r2 = 0; r2 < 4; ++r2)
      tbT[(nt * 16 + rl) * 72 + wv * 16 + q * 4 + r2] = f2bf(acc[nt][r2]);
  __syncthreads();
  // emit whT[col][j] coalesced; col 63 = ones (denominator)
  {
    const int col = t & 63, half = t >> 6;
    uint4 o0 = *(const uint4*)&tbT[col * 72 + half * 16];
    uint4 o1 = *(const uint4*)&tbT[col * 72 + half * 16 + 8];
    if (col == 63) {
      o0.x = o0.y = o0.z = o0.w = 0x3f803f80u;
      o1 = o0;
    }
    unsigned short* dst = whT + (((size_t)hh * B_ + bb) * 64 + col) * 512 + n0 + half * 16;
    *(uint4*)dst = o0;
    *(uint4*)(dst + 8) = o1;
  }
}

// ---------- K3s: layer-1 attention, 16-row blocks, 4-wave j-split ------------------
__global__ __launch_bounds__(256) void k3s(const unsigned short* __restrict__ whT,
                                           const float* __restrict__ e1,
                                           const float* __restrict__ e2,
                                           const u64* __restrict__ maskw,
                                           const float* __restrict__ wv1,
                                           const float* __restrict__ wv2,
                                           unsigned short* __restrict__ catbf,
                                           float* __restrict__ e1p,
                                           float* __restrict__ e2p) {
  __shared__ __align__(16) float e2s[N_];
  __shared__ __align__(16) float red[4][64][17];
  int x = (int)((blockIdx.x & 7) * 384 + (blockIdx.x >> 3));  // bijective (3072%8==0)
  const int hh = x >> 10;
  const int bb = (x >> 5) & 31;
  const int rg = x & 31;
  const int n0 = rg * 16;
  const int t = threadIdx.x;
  const int l = t & 63, wid = t >> 6;
  const int q = l >> 4, rl = l & 15;

  const float* e2pp = e2 + ((size_t)hh * B_ + bb) * N_;
  for (int i = t; i < N_ / 4; i += 256) ((float4*)e2s)[i] = ((const float4*)e2pp)[i];
  __syncthreads();

  const int row = n0 + rl;
  const float e1r = e1[((size_t)hh * B_ + bb) * N_ + row];
  const u64* mr = maskw + ((size_t)bb * N_ + row) * 8;

  f32x4 acc[4];
  #pragma unroll
  for (int c = 0; c < 4; ++c) acc[c] = (f32x4){0.f, 0.f, 0.f, 0.f};
  const unsigned short* wb = whT + ((size_t)hh * B_ + bb) * 64 * 512;

  #pragma unroll
  for (int tts = 0; tts < 2; ++tts) {
    const int tt = wid * 2 + tts;
    short8 bf[4][2];
    #pragma unroll
    for (int c = 0; c < 4; ++c) {
      const unsigned short* bp = wb + (size_t)(c * 16 + rl) * 512 + tt * 64 + q * 8;
      bf[c][0] = *(const short8*)bp;
      bf[c][1] = *(const short8*)(bp + 32);
    }
    u64 word = mr[tt];
    short8 af0 = build_af(e2s, e1r, word, tt * 64 + q * 8, q * 8);
    short8 af1 = build_af(e2s, e1r, word, tt * 64 + 32 + q * 8, 32 + q * 8);
    #pragma unroll
    for (int c = 0; c < 4; ++c) {
      acc[c] = __builtin_amdgcn_mfma_f32_16x16x32_bf16(af0, bf[c][0], acc[c], 0, 0, 0);
      acc[c] = __builtin_amdgcn_mfma_f32_16x16x32_bf16(af1, bf[c][1], acc[c], 0, 0, 0);
    }
  }

  #pragma unroll
  for (int c = 0; c < 4; ++c)
    #pragma unroll
    for (int r = 0; r < 4; ++r) red[wid][l][c * 4 + r] = acc[c][r];
  __syncthreads();

  if (wid == 0) {
    #pragma unroll
    for (int c = 0; c < 4; ++c)
      #pragma unroll
      for (int r = 0; r < 4; ++r)
        acc[c][r] = red[0][l][c * 4 + r] + red[1][l][c * 4 + r] +
                    red[2][l][c * 4 + r] + red[3][l][c * 4 + r];
    float w1c[4], w2c[4];
    #pragma unroll
    for (int c = 0; c < 4; ++c) {
      const int col = c * 16 + rl;
      w1c[c] = (col < FH_) ? wv1[hh * FH_ + col] : 0.f;
      w2c[c] = (col < FH_) ? wv2[hh * FH_ + col] : 0.f;
    }
    #pragma unroll
    for (int r = 0; r < 4; ++r) {
      float srow = __shfl(acc[3][r], (q << 4) | 15);  // col 63 = denom (ones col)
      float invr = srow > 0.f ? 1.f / srow : 0.f;
      const size_t grow = (size_t)bb * N_ + n0 + q * 4 + r;
      float p1 = 0.f, p2 = 0.f;
      #pragma unroll
      for (int c = 0; c < 4; ++c) {
        const int col = c * 16 + rl;
        if (col < FH_) {
          float v = acc[c][r] * invr;
          v = v > 0.f ? v : __expf(v) - 1.f;  // ELU
          catbf[grow * KP_ + hh * FH_ + col] = f2bf(v);
          p1 += v * w1c[c];
          p2 += v * w2c[c];
        }
      }
      p1 += __shfl_xor(p1, 1); p1 += __shfl_xor(p1, 2);
      p1 += __shfl_xor(p1, 4); p1 += __shfl_xor(p1, 8);
      p2 += __shfl_xor(p2, 1); p2 += __shfl_xor(p2, 2);
      p2 += __shfl_xor(p2, 4); p2 += __shfl_xor(p2, 8);
      if (rl == 0) {
        e1p[(size_t)hh * (B_ * N_) + grow] = p1;
        e2p[(size_t)hh * (B_ * N_) + grow] = p2;
      }
    }
  }
  if (hh == 2 && t < 16) {  // zero-pad K cols 150..159 for this block's 16 rows
    const size_t grow = (size_t)bb * N_ + n0 + t;
    unsigned* zp = (unsigned*)&catbf[grow * KP_ + CAT_];
    #pragma unroll
    for (int i = 0; i < 5; ++i) zp[i] = 0u;
  }
}

// ---------- K4: Wh2 = catbf @ WoutT via MFMA (cols 0..79); fill 80..95 -------------
__global__ __launch_bounds__(256) void k4_gemm2(const unsigned short* __restrict__ catbf,
                                                const unsigned short* __restrict__ WoutT,
                                                unsigned short* __restrict__ wh2T) {
  const int t = threadIdx.x, l = t & 63, wid = t >> 6;
  const int q = l >> 4, rl = l & 15;
  const int blk = blockIdx.x;
  const int jbase = blk * 64 + wid * 16;
  f32x4 acc[5];
  #pragma unroll
  for (int nt = 0; nt < 5; ++nt) acc[nt] = (f32x4){0.f, 0.f, 0.f, 0.f};
  const unsigned short* ap = catbf + (size_t)(jbase + rl) * KP_ + q * 8;
  #pragma unroll
  for (int kk = 0; kk < 5; ++kk) {
    short8 a = *(const short8*)(ap + kk * 32);
    #pragma unroll
    for (int nt = 0; nt < 5; ++nt) {
      short8 b = *(const short8*)&WoutT[(size_t)(nt * 16 + rl) * KP_ + kk * 32 + q * 8];
      acc[nt] = __builtin_amdgcn_mfma_f32_16x16x32_bf16(a, b, acc[nt], 0, 0, 0);
    }
  }
  const int bb = blk >> 3, jt = blk & 7;
  const int j0 = jt * 64 + wid * 16 + q * 4;
  #pragma unroll
  for (int nt = 0; nt < 5; ++nt) {
    const int col = nt * 16 + rl;
    unsigned short pk[4];
    #pragma unroll
    for (int r = 0; r < 4; ++r) pk[r] = f2bf(acc[nt][r]);
    uint2 o;
    o.x = (unsigned)pk[0] | ((unsigned)pk[1] << 16);
    o.y = (unsigned)pk[2] | ((unsigned)pk[3] << 16);
    *(uint2*)&wh2T[((size_t)bb * NP_ + col) * 512 + j0] = o;
  }
  {
    const int col = 80 + (t >> 4), jq = (t & 15) * 4;
    unsigned fill = (col == 95) ? 0x3f803f80u : 0u;
    uint2 o; o.x = fill; o.y = fill;
    *(uint2*)&wh2T[((size_t)bb * NP_ + col) * 512 + jt * 64 + jq] = o;
  }
}

// ---------- K5: layer-2 attention, 16-row blocks, 4-wave j-split -------------------
__global__ __launch_bounds__(256) void k5_attn2(const unsigned short* __restrict__ wh2T,
                                                const float* __restrict__ e1p,
                                                const float* __restrict__ e2p,
                                                const u64* __restrict__ maskw,
                                                float* __restrict__ out) {
  __shared__ __align__(16) float e2s[N_];
  __shared__ __align__(16) float red[4][64][25];
  int x = (int)((blockIdx.x & 7) * 128 + (blockIdx.x >> 3));
  const int rg = x & 31;
  const int bb = x >> 5;
  const int n0 = rg * 16;
  const int t = threadIdx.x;
  const int l = t & 63, wid = t >> 6;
  const int q = l >> 4, rl = l & 15;

  for (int i = t; i < N_ / 4; i += 256) {
    float4 v0 = ((const float4*)(e2p))[(size_t)bb * 128 + i];
    float4 v1 = ((const float4*)(e2p + B_ * N_))[(size_t)bb * 128 + i];
    float4 v2 = ((const float4*)(e2p + 2 * B_ * N_))[(size_t)bb * 128 + i];
    float4 s;
    s.x = v0.x + v1.x + v2.x; s.y = v0.y + v1.y + v2.y;
    s.z = v0.z + v1.z + v2.z; s.w = v0.w + v1.w + v2.w;
    ((float4*)e2s)[i] = s;
  }
  __syncthreads();

  const int row = n0 + rl;
  const size_t gr = (size_t)bb * N_ + row;
  const float e1r = e1p[gr] + e1p[B_ * N_ + gr] + e1p[2 * B_ * N_ + gr];
  const u64* mr = maskw + gr * 8;

  f32x4 acc[6];
  #pragma unroll
  for (int c = 0; c < 6; ++c) acc[c] = (f32x4){0.f, 0.f, 0.f, 0.f};
  const unsigned short* wb = wh2T + (size_t)bb * NP_ * 512;

  #pragma unroll
  for (int tts = 0; tts < 2; ++tts) {
    const int tt = wid * 2 + tts;
    short8 bf[6][2];
    #pragma unroll
    for (int c = 0; c < 6; ++c) {
      const unsigned short* bp = wb + (size_t)(c * 16 + rl) * 512 + tt * 64 + q * 8;
      bf[c][0] = *(const short8*)bp;
      bf[c][1] = *(const short8*)(bp + 32);
    }
    u64 word = mr[tt];
    short8 af0 = build_af(e2s, e1r, word, tt * 64 + q * 8, q * 8);
    short8 af1 = build_af(e2s, e1r, word, tt * 64 + 32 + q * 8, 32 + q * 8);
    #pragma unroll
    for (int c = 0; c < 6; ++c) {
      acc[c] = __builtin_amdgcn_mfma_f32_16x16x32_bf16(af0, bf[c][0], acc[c], 0, 0, 0);
      acc[c] = __builtin_amdgcn_mfma_f32_16x16x32_bf16(af1, bf[c][1], acc[c], 0, 0, 0);
    }
  }

  #pragma unroll
  for (int c = 0; c < 6; ++c)
    #pragma unroll
    for (int r = 0; r < 4; ++r) red[wid][l][c * 4 + r] = acc[c][r];
  __syncthreads();

  if (wid == 0) {
    #pragma unroll
    for (int c = 0; c < 6; ++c)
      #pragma unroll
      for (int r = 0; r < 4; ++r)
        acc[c][r] = red[0][l][c * 4 + r] + red[1][l][c * 4 + r] +
                    red[2][l][c * 4 + r] + red[3][l][c * 4 + r];
    const size_t orow0 = (size_t)bb * N_ + n0;
    #pragma unroll
    for (int r = 0; r < 4; ++r) {
      float srow = __shfl(acc[5][r], (q << 4) | 15);  // col 95 = denom
      float invr = srow > 0.f ? 1.f / srow : 0.f;
      const size_t ob = (orow0 + q * 4 + r) * FO_;
      #pragma unroll
      for (int c = 0; c < 5; ++c) out[ob + c * 16 + rl] = acc[c][r] * invr;
    }
  }
}

extern "C" void kernel_launch(void* const* d_in, const int* in_sizes, int n_in,
                              void* d_out, int out_size, void* d_ws, size_t ws_size,
                              hipStream_t stream) {
  const float* h    = (const float*)d_in[0];
  const int*   adj  = (const int*)d_in[1];
  const float* Ws   = (const float*)d_in[2];
  const float* aa   = (const float*)d_in[3];
  const float* Wout = (const float*)d_in[4];
  const float* aout = (const float*)d_in[5];

  char* ws = (char*)d_ws;
  unsigned short* whT   = (unsigned short*)(ws + 0);         // 6,291,456
  float* e1h            = (float*)(ws + 6291456);            //   196,608
  float* e2h            = (float*)(ws + 6488064);            //   196,608
  u64*   mk             = (u64*)  (ws + 6684672);            // 1,048,576
  unsigned short* catbf = (unsigned short*)(ws + 7733248);   // 5,242,880
  unsigned short* WoutT = (unsigned short*)(ws + 12976128);  //    30,720
  float* wv1            = (float*)(ws + 13008896);           //     1,024
  float* wv2            = (float*)(ws + 13009920);           //     1,024
  float* e1p            = (float*)(ws + 13010944);           //   196,608
  float* e2p            = (float*)(ws + 13207552);           //   196,608
  unsigned short* wh2T  = (unsigned short*)(ws + 13404160);  // 3,145,728
  unsigned short* WsT   = (unsigned short*)(ws + 16549888);  //    36,864
  float* wa1g           = (float*)(ws + 16586752);           //     1,024
  float* wa2g           = (float*)(ws + 16587776);           //     1,024

  hipLaunchKernelGGL(k0_maskprep, dim3(2074), dim3(256), 0, stream,
                     adj, Ws, aa, Wout, aout, mk, WsT, wa1g, wa2g, WoutT, wv1, wv2);
  hipLaunchKernelGGL(k1_mfma, dim3(768), dim3(256), 0, stream,
                     h, WsT, wa1g, wa2g, whT, e1h, e2h);
  hipLaunchKernelGGL(k3s, dim3(3072), dim3(256), 0, stream,
                     whT, e1h, e2h, mk, wv1, wv2, catbf, e1p, e2p);
  hipLaunchKernelGGL(k4_gemm2, dim3(256), dim3(256), 0, stream, catbf, WoutT, wh2T);
  hipLaunchKernelGGL(k5_attn2, dim3(1024), dim3(256), 0, stream,
                     wh2T, e1p, e2p, mk, (float*)d_out);
}